// Round 8
// baseline (45.861 us; speedup 1.0000x reference)
//
#include <hip/hip_runtime.h>
#include <math.h>
#include <stdint.h>

// Cox partial-likelihood loss, N = 16384 — SINGLE-DISPATCH producer/consumer.
//   T = |y|, E = (y > 0), theta = y_hat, e = exp(theta)
//   risk[i] = sum over 64 sorted chunks c of suffix_c[ lower_bound_c(T_i) ]
//   loss = -mean((theta - log(risk)) * E)
//
// 256 blocks x 1024 thr, 132 KB LDS -> 1 block/CU, grid == #CUs: every block
// gets an idle CU at dispatch; spins never prevent another block's residency
// -> deadlock-free without cooperative launch.
//
// Replay-idempotent MAGIC-flag protocol (ws poisoned 0xAA once, never reset):
// every ws write is value-identical across replays, so a consumer passing a
// stale MAGIC flag early reads identical bytes; first call is gated because
// poison != MAGIC. Cross-XCD visibility via agent-scope atomics (per-XCD L2s
// are not coherent). out[0] is plain-stored by block 0 only (no accumulation,
// no zero-init).

#define CSZ     256
#define NCH     64
#define N_      16384
#define IPB     64
#define THREADS 1024
#define NBLK    256
#define MAGIC   0x5EEDF00Du

typedef unsigned int u32;
typedef unsigned long long u64;

__device__ __forceinline__ u64 shflxor64(u64 v, int m) {
    u32 lo = __shfl_xor((u32)v, m, 64);
    u32 hi = __shfl_xor((u32)(v >> 32), m, 64);
    return ((u64)hi << 32) | (u64)lo;
}

__global__ void __launch_bounds__(THREADS) cox_one(
        const float* __restrict__ y_hat, const float* __restrict__ y,
        u32* __restrict__ wsT, u32* __restrict__ wsS,
        u32* __restrict__ flags, u64* __restrict__ slots,
        float* __restrict__ out, int n) {
    __shared__ float sT[N_];              // 64 KB sorted T
    __shared__ float sS[N_];              // 64 KB suffix sums
    __shared__ float part[16][IPB];       // 4 KB

    const int tid  = threadIdx.x;
    const int lane = tid & 63;
    const int wv   = tid >> 6;            // 0..15
    const int b    = blockIdx.x;

    // ---------- produce: blocks 0..63, wave 0 sorts chunk b ----------
    if (b < NCH && wv == 0) {
        const int cbase = b << 8;
        // element position e = (r<<6)|lane; key = T-bits (hi) | e-bits (lo).
        // T >= 0 so float bits are unsigned-monotonic; low-bits tie-break only
        // permutes equal-T elements (suffix sums invariant).
        u64 key[4];
        #pragma unroll
        for (int r = 0; r < 4; ++r) {
            const int idx = cbase + (r << 6) + lane;
            const float t  = fabsf(y[idx]);
            const float ex = expf(y_hat[idx]);
            key[r] = ((u64)__float_as_uint(t) << 32) | (u64)__float_as_uint(ex);
        }
        // bitonic sort ascending over e (same up/lower/takeMin algebra that
        // validated in R7, with e in place of tid)
        #pragma unroll
        for (int k = 2; k <= CSZ; k <<= 1) {
            #pragma unroll
            for (int j = k >> 1; j > 0; j >>= 1) {
                if (j >= 64) {                       // partner differs in r bits
                    const int rm = j >> 6;           // 1 or 2
                    #pragma unroll
                    for (int r = 0; r < 4; ++r) {
                        if ((r & rm) == 0) {
                            const int r2 = r | rm;
                            const bool asc = ((((unsigned)r << 6) & (unsigned)k) == 0);
                            u64 a = key[r], c2 = key[r2];
                            u64 mn = a < c2 ? a : c2;
                            u64 mx = a < c2 ? c2 : a;
                            key[r]  = asc ? mn : mx;
                            key[r2] = asc ? mx : mn;
                        }
                    }
                } else {                             // partner differs in lane bits
                    #pragma unroll
                    for (int r = 0; r < 4; ++r) {
                        const unsigned e = ((unsigned)r << 6) | (unsigned)lane;
                        const bool up      = ((e & (unsigned)k) == 0);
                        const bool lower   = ((e & (unsigned)j) == 0);
                        const bool keepMin = (lower == up);
                        u64 p  = shflxor64(key[r], j);
                        u64 mn = key[r] < p ? key[r] : p;
                        u64 mx = key[r] < p ? p : key[r];
                        key[r] = keepMin ? mn : mx;
                    }
                }
            }
        }
        // inclusive suffix sums of e-values, in registers
        float s4[4];
        #pragma unroll
        for (int r = 0; r < 4; ++r) {
            float v = __uint_as_float((u32)key[r]);
            #pragma unroll
            for (int d = 1; d < 64; d <<= 1) {
                float t2 = __shfl_down(v, d, 64);
                if (lane + d < 64) v += t2;
            }
            s4[r] = v;                    // suffix within 64-segment r
        }
        const float tot1 = __shfl(s4[1], 0, 64);
        const float tot2 = __shfl(s4[2], 0, 64);
        const float tot3 = __shfl(s4[3], 0, 64);
        s4[0] += tot1 + tot2 + tot3;
        s4[1] += tot2 + tot3;
        s4[2] += tot3;
        // publish chunk tables (agent scope -> coherent point), then flag
        #pragma unroll
        for (int r = 0; r < 4; ++r) {
            const int p = cbase + (r << 6) + lane;
            __hip_atomic_store(&wsT[p], (u32)(key[r] >> 32),
                               __ATOMIC_RELAXED, __HIP_MEMORY_SCOPE_AGENT);
            __hip_atomic_store(&wsS[p], __float_as_uint(s4[r]),
                               __ATOMIC_RELAXED, __HIP_MEMORY_SCOPE_AGENT);
        }
        if (lane == 0)
            __hip_atomic_store(&flags[b], MAGIC, __ATOMIC_RELEASE,
                               __HIP_MEMORY_SCOPE_AGENT);
    }

    // ---------- consume: all 256 blocks ----------
    if (tid < NCH) {
        while (__hip_atomic_load(&flags[tid], __ATOMIC_RELAXED,
                                 __HIP_MEMORY_SCOPE_AGENT) != MAGIC)
            __builtin_amdgcn_s_sleep(1);
    }
    __syncthreads();
    __builtin_amdgcn_fence(__ATOMIC_ACQUIRE, "agent");

    // stage tables into LDS via agent-scope loads (skip stale local L2)
    for (int w = tid; w < N_; w += THREADS) {
        sT[w] = __uint_as_float(__hip_atomic_load(&wsT[w], __ATOMIC_RELAXED,
                                                  __HIP_MEMORY_SCOPE_AGENT));
        sS[w] = __uint_as_float(__hip_atomic_load(&wsS[w], __ATOMIC_RELAXED,
                                                  __HIP_MEMORY_SCOPE_AGENT));
    }
    __syncthreads();

    // search: group wv handles chunks 4wv..4wv+3 for i = b*64 + lane
    const int i = b * IPB + lane;
    const float Ti = fabsf(y[i]);
    float racc = 0.0f;
    #pragma unroll
    for (int cc = 0; cc < 4; ++cc) {
        const int c = (wv << 2) + cc;
        const float* Tc = &sT[c << 8];
        int pos = 0;
        #pragma unroll
        for (int half = CSZ >> 1; half >= 1; half >>= 1)
            if (Tc[pos + half - 1] < Ti) pos += half;
        if (Tc[pos] < Ti) pos += 1;
        racc += (pos < CSZ) ? sS[(c << 8) + pos] : 0.0f;
    }
    part[wv][lane] = racc;
    __syncthreads();

    if (tid < IPB) {
        float risk = 0.0f;
        #pragma unroll
        for (int g2 = 0; g2 < 16; ++g2) risk += part[g2][tid];
        const int ii = b * IPB + tid;
        const float E = (y[ii] > 0.0f) ? 1.0f : 0.0f;
        float term = (y_hat[ii] - logf(risk)) * E;
        #pragma unroll
        for (int off = 32; off >= 1; off >>= 1)
            term += __shfl_down(term, off, 64);
        if (tid == 0) {
            const u64 payload = ((u64)MAGIC << 32) | (u64)__float_as_uint(term);
            __hip_atomic_store(&slots[b], payload, __ATOMIC_RELAXED,
                               __HIP_MEMORY_SCOPE_AGENT);
        }
        // block 0: final reduction of 256 partials (payload carries its flag)
        if (b == 0) {
            float acc = 0.0f;
            #pragma unroll
            for (int q = 0; q < 4; ++q) {
                const int s5 = (q << 6) | tid;
                u64 v;
                for (;;) {
                    v = __hip_atomic_load(&slots[s5], __ATOMIC_RELAXED,
                                          __HIP_MEMORY_SCOPE_AGENT);
                    if ((u32)(v >> 32) == MAGIC) break;
                    __builtin_amdgcn_s_sleep(1);
                }
                acc += __uint_as_float((u32)(v & 0xFFFFFFFFull));
            }
            #pragma unroll
            for (int off = 32; off >= 1; off >>= 1)
                acc += __shfl_down(acc, off, 64);
            if (tid == 0) out[0] = -acc / (float)n;
        }
    }
}

extern "C" void kernel_launch(void* const* d_in, const int* in_sizes, int n_in,
                              void* d_out, int out_size, void* d_ws, size_t ws_size,
                              hipStream_t stream) {
    const float* y_hat = (const float*)d_in[0];
    const float* y     = (const float*)d_in[1];
    float* out = (float*)d_out;
    const int n = in_sizes[0];   // 16384

    u32* wsT   = (u32*)d_ws;                 // 16384 words
    u32* wsS   = wsT + N_;                   // 16384 words
    u32* flags = wsS + N_;                   // 64 words
    u64* slots = (u64*)(flags + 64);         // 256 u64 (8-byte aligned: 131328 % 8 == 0)

    cox_one<<<NBLK, THREADS, 0, stream>>>(y_hat, y, wsT, wsS, flags, slots, out, n);
}

// Round 9
// 43.367 us; speedup vs baseline: 1.0575x; 1.0575x over previous
//
#include <hip/hip_runtime.h>
#include <math.h>
#include <stdint.h>

// Cox partial-likelihood loss, N = 16384 — SINGLE-DISPATCH producer/consumer.
//   T = |y|, E = (y > 0), theta = y_hat, e = exp(theta)
//   risk[i] = sum over 64 sorted chunks c of suffix_c[ lower_bound_c(T_i) ]
//   loss = -mean((theta - log(risk)) * E)
//
// 256 blocks x 1024 thr, 132 KB LDS -> 1 block/CU, grid == #CUs: every block
// gets an idle CU at dispatch -> spin-waits deadlock-free without coop launch.
//
// Replay-idempotent MAGIC-flag protocol (ws poisoned once, never re-poisoned):
// all ws writes are value-identical across replays, so a stale MAGIC read
// yields identical bytes; first call gated because poison != MAGIC.
//
// R9 transport fix vs R8: bulk tables move via PLAIN stores/loads bracketed by
// agent-scope fences (release: L2 writeback before flag; acquire: L1/L2
// invalidate after flag) instead of per-word atomic loads (R8: 8.4M atomic
// ops = 50 us on the atomic slow path). Only flags/slots stay atomic.

#define CSZ     256
#define NCH     64
#define N_      16384
#define IPB     64
#define THREADS 1024
#define NBLK    256
#define MAGIC   0x5EEDF00Du

typedef unsigned int u32;
typedef unsigned long long u64;

__device__ __forceinline__ u64 shflxor64(u64 v, int m) {
    u32 lo = __shfl_xor((u32)v, m, 64);
    u32 hi = __shfl_xor((u32)(v >> 32), m, 64);
    return ((u64)hi << 32) | (u64)lo;
}

__global__ void __launch_bounds__(THREADS) cox_one(
        const float* __restrict__ y_hat, const float* __restrict__ y,
        float* __restrict__ wsT, float* __restrict__ wsS,
        u32* __restrict__ flags, u64* __restrict__ slots,
        float* __restrict__ out, int n) {
    __shared__ float sT[N_];              // 64 KB sorted T
    __shared__ float sS[N_];              // 64 KB suffix sums
    __shared__ float part[16][IPB];       // 4 KB

    const int tid  = threadIdx.x;
    const int lane = tid & 63;
    const int wv   = tid >> 6;            // 0..15
    const int b    = blockIdx.x;

    // ---------- produce: blocks 0..63, wave 0 sorts chunk b ----------
    if (b < NCH && wv == 0) {
        const int cbase = b << 8;
        // element position e = (r<<6)|lane; key = T-bits (hi) | e-bits (lo).
        // T >= 0 so float bits are unsigned-monotonic; low-bits tie-break only
        // permutes equal-T elements (suffix sums invariant).
        u64 key[4];
        #pragma unroll
        for (int r = 0; r < 4; ++r) {
            const int idx = cbase + (r << 6) + lane;
            const float t  = fabsf(y[idx]);
            const float ex = expf(y_hat[idx]);
            key[r] = ((u64)__float_as_uint(t) << 32) | (u64)__float_as_uint(ex);
        }
        // bitonic sort ascending (validated in R8)
        #pragma unroll
        for (int k = 2; k <= CSZ; k <<= 1) {
            #pragma unroll
            for (int j = k >> 1; j > 0; j >>= 1) {
                if (j >= 64) {                       // partner differs in r bits
                    const int rm = j >> 6;           // 1 or 2
                    #pragma unroll
                    for (int r = 0; r < 4; ++r) {
                        if ((r & rm) == 0) {
                            const int r2 = r | rm;
                            const bool asc = ((((unsigned)r << 6) & (unsigned)k) == 0);
                            u64 a = key[r], c2 = key[r2];
                            u64 mn = a < c2 ? a : c2;
                            u64 mx = a < c2 ? c2 : a;
                            key[r]  = asc ? mn : mx;
                            key[r2] = asc ? mx : mn;
                        }
                    }
                } else {                             // partner differs in lane bits
                    #pragma unroll
                    for (int r = 0; r < 4; ++r) {
                        const unsigned e = ((unsigned)r << 6) | (unsigned)lane;
                        const bool up      = ((e & (unsigned)k) == 0);
                        const bool lower   = ((e & (unsigned)j) == 0);
                        const bool keepMin = (lower == up);
                        u64 p  = shflxor64(key[r], j);
                        u64 mn = key[r] < p ? key[r] : p;
                        u64 mx = key[r] < p ? p : key[r];
                        key[r] = keepMin ? mn : mx;
                    }
                }
            }
        }
        // inclusive suffix sums of e-values, in registers
        float s4[4];
        #pragma unroll
        for (int r = 0; r < 4; ++r) {
            float v = __uint_as_float((u32)key[r]);
            #pragma unroll
            for (int d = 1; d < 64; d <<= 1) {
                float t2 = __shfl_down(v, d, 64);
                if (lane + d < 64) v += t2;
            }
            s4[r] = v;                    // suffix within 64-segment r
        }
        const float tot1 = __shfl(s4[1], 0, 64);
        const float tot2 = __shfl(s4[2], 0, 64);
        const float tot3 = __shfl(s4[3], 0, 64);
        s4[0] += tot1 + tot2 + tot3;
        s4[1] += tot2 + tot3;
        s4[2] += tot3;
        // publish chunk tables: PLAIN coalesced stores, then release fence
        // (L2 writeback to coherent point), then MAGIC flag.
        #pragma unroll
        for (int r = 0; r < 4; ++r) {
            const int p = cbase + (r << 6) + lane;
            wsT[p] = __uint_as_float((u32)(key[r] >> 32));
            wsS[p] = s4[r];
        }
        __builtin_amdgcn_fence(__ATOMIC_RELEASE, "agent");
        if (lane == 0)
            __hip_atomic_store(&flags[b], MAGIC, __ATOMIC_RELAXED,
                               __HIP_MEMORY_SCOPE_AGENT);
    }

    // ---------- consume: all 256 blocks ----------
    if (tid < NCH) {
        while (__hip_atomic_load(&flags[tid], __ATOMIC_RELAXED,
                                 __HIP_MEMORY_SCOPE_AGENT) != MAGIC)
            __builtin_amdgcn_s_sleep(1);
    }
    __syncthreads();
    // acquire: invalidate stale L1/L2 lines so plain loads see producer data
    __builtin_amdgcn_fence(__ATOMIC_ACQUIRE, "agent");

    // stage tables into LDS: plain float4 loads (L3-served, 1 KB/wave-instr)
    {
        const float4* gT = (const float4*)wsT;
        const float4* gS = (const float4*)wsS;
        float4* lT = (float4*)sT;
        float4* lS = (float4*)sS;
        #pragma unroll
        for (int k = tid; k < N_ / 4; k += THREADS) {
            lT[k] = gT[k];
            lS[k] = gS[k];
        }
    }
    __syncthreads();

    // search: group wv handles chunks 4wv..4wv+3 for i = b*64 + lane
    const int i = b * IPB + lane;
    const float Ti = fabsf(y[i]);
    float racc = 0.0f;
    #pragma unroll
    for (int cc = 0; cc < 4; ++cc) {
        const int c = (wv << 2) + cc;
        const float* Tc = &sT[c << 8];
        int pos = 0;
        #pragma unroll
        for (int half = CSZ >> 1; half >= 1; half >>= 1)
            if (Tc[pos + half - 1] < Ti) pos += half;
        if (Tc[pos] < Ti) pos += 1;
        racc += (pos < CSZ) ? sS[(c << 8) + pos] : 0.0f;
    }
    part[wv][lane] = racc;
    __syncthreads();

    if (tid < IPB) {
        float risk = 0.0f;
        #pragma unroll
        for (int g2 = 0; g2 < 16; ++g2) risk += part[g2][tid];
        const int ii = b * IPB + tid;
        const float E = (y[ii] > 0.0f) ? 1.0f : 0.0f;
        float term = (y_hat[ii] - logf(risk)) * E;
        #pragma unroll
        for (int off = 32; off >= 1; off >>= 1)
            term += __shfl_down(term, off, 64);
        if (tid == 0) {
            const u64 payload = ((u64)MAGIC << 32) | (u64)__float_as_uint(term);
            __hip_atomic_store(&slots[b], payload, __ATOMIC_RELAXED,
                               __HIP_MEMORY_SCOPE_AGENT);
        }
        // block 0: final reduction of 256 partials (payload carries its flag)
        if (b == 0) {
            float acc = 0.0f;
            #pragma unroll
            for (int q = 0; q < 4; ++q) {
                const int s5 = (q << 6) | tid;
                u64 v;
                for (;;) {
                    v = __hip_atomic_load(&slots[s5], __ATOMIC_RELAXED,
                                          __HIP_MEMORY_SCOPE_AGENT);
                    if ((u32)(v >> 32) == MAGIC) break;
                    __builtin_amdgcn_s_sleep(1);
                }
                acc += __uint_as_float((u32)(v & 0xFFFFFFFFull));
            }
            #pragma unroll
            for (int off = 32; off >= 1; off >>= 1)
                acc += __shfl_down(acc, off, 64);
            if (tid == 0) out[0] = -acc / (float)n;
        }
    }
}

extern "C" void kernel_launch(void* const* d_in, const int* in_sizes, int n_in,
                              void* d_out, int out_size, void* d_ws, size_t ws_size,
                              hipStream_t stream) {
    const float* y_hat = (const float*)d_in[0];
    const float* y     = (const float*)d_in[1];
    float* out = (float*)d_out;
    const int n = in_sizes[0];   // 16384

    float* wsT   = (float*)d_ws;             // 16384 words
    float* wsS   = wsT + N_;                 // 16384 words
    u32*   flags = (u32*)(wsS + N_);         // 64 words
    u64*   slots = (u64*)(flags + 64);       // 256 u64 (131328 % 8 == 0)

    cox_one<<<NBLK, THREADS, 0, stream>>>(y_hat, y, wsT, wsS, flags, slots, out, n);
}

// Round 10
// 22.016 us; speedup vs baseline: 2.0831x; 1.9698x over previous
//
#include <hip/hip_runtime.h>
#include <math.h>
#include <stdint.h>

// Cox partial-likelihood loss, N = 16384 — two-dispatch sorted-chunk scheme.
//   T = |y|, E = (y > 0), theta = y_hat, e = exp(theta)
//   risk[i] = sum over 64 sorted chunks c of suffix_c[ lower_bound_c(T_i) ]
//   loss = -mean((theta - log(risk)) * E)
//
// K0: 64 blocks x 64 thr (one wave per chunk) — u64-key (T-bits||e-bits)
//     register bitonic sort, zero LDS, zero barriers (validated R8/R9);
//     in-register suffix sums; plain stores (dispatch boundary = visibility).
// K1: 256 blocks x 1024 thr — stages both 64 KB tables into LDS via
//     __builtin_amdgcn_global_load_lds (16 B, no VGPR round-trip); thread
//     group wv searches 4 chunks for i = b*64+lane; LDS reduce across groups;
//     wave 0 reuses its in-register yh/E for the loss term; one atomicAdd.

#define CSZ     256
#define NCH     64
#define N_      16384
#define IPB     64
#define THREADS 1024

typedef unsigned int u32;
typedef unsigned long long u64;

__device__ __forceinline__ u64 shflxor64(u64 v, int m) {
    u32 lo = __shfl_xor((u32)v, m, 64);
    u32 hi = __shfl_xor((u32)(v >> 32), m, 64);
    return ((u64)hi << 32) | (u64)lo;
}

// async global->LDS, 16 bytes/lane; lds must be wave-uniform, lane i lands at
// lds + i*16 (linear). Completion tracked by vmcnt; __syncthreads() drains it.
__device__ __forceinline__ void g2l16(const void* g, void* l) {
    __builtin_amdgcn_global_load_lds(
        (const __attribute__((address_space(1))) void*)g,
        (__attribute__((address_space(3))) void*)l, 16, 0, 0);
}

// ---------------- K0: register bitonic sort + suffix scan ----------------
__global__ void __launch_bounds__(64) cox_sort(
        const float* __restrict__ y_hat, const float* __restrict__ y,
        float* __restrict__ wsT, float* __restrict__ wsS,
        float* __restrict__ out) {
    const int lane  = threadIdx.x;
    const int b     = blockIdx.x;
    const int cbase = b << 8;

    if (b == 0 && lane == 0) out[0] = 0.0f;

    // element position e = (r<<6)|lane; key = T-bits (hi) | e-bits (lo).
    // T >= 0 so float bits are unsigned-monotonic; low-bits tie-break only
    // permutes equal-T elements (suffix sums invariant).
    u64 key[4];
    #pragma unroll
    for (int r = 0; r < 4; ++r) {
        const int idx = cbase + (r << 6) + lane;
        const float t  = fabsf(y[idx]);
        const float ex = expf(y_hat[idx]);
        key[r] = ((u64)__float_as_uint(t) << 32) | (u64)__float_as_uint(ex);
    }
    // bitonic sort ascending (validated R8/R9)
    #pragma unroll
    for (int k = 2; k <= CSZ; k <<= 1) {
        #pragma unroll
        for (int j = k >> 1; j > 0; j >>= 1) {
            if (j >= 64) {                       // partner differs in r bits
                const int rm = j >> 6;           // 1 or 2
                #pragma unroll
                for (int r = 0; r < 4; ++r) {
                    if ((r & rm) == 0) {
                        const int r2 = r | rm;
                        const bool asc = ((((unsigned)r << 6) & (unsigned)k) == 0);
                        u64 a = key[r], c2 = key[r2];
                        u64 mn = a < c2 ? a : c2;
                        u64 mx = a < c2 ? c2 : a;
                        key[r]  = asc ? mn : mx;
                        key[r2] = asc ? mx : mn;
                    }
                }
            } else {                             // partner differs in lane bits
                #pragma unroll
                for (int r = 0; r < 4; ++r) {
                    const unsigned e = ((unsigned)r << 6) | (unsigned)lane;
                    const bool up      = ((e & (unsigned)k) == 0);
                    const bool lower   = ((e & (unsigned)j) == 0);
                    const bool keepMin = (lower == up);
                    u64 p  = shflxor64(key[r], j);
                    u64 mn = key[r] < p ? key[r] : p;
                    u64 mx = key[r] < p ? p : key[r];
                    key[r] = keepMin ? mn : mx;
                }
            }
        }
    }
    // inclusive suffix sums of e-values, in registers
    float s4[4];
    #pragma unroll
    for (int r = 0; r < 4; ++r) {
        float v = __uint_as_float((u32)key[r]);
        #pragma unroll
        for (int d = 1; d < 64; d <<= 1) {
            float t2 = __shfl_down(v, d, 64);
            if (lane + d < 64) v += t2;
        }
        s4[r] = v;                    // suffix within 64-segment r
    }
    const float tot1 = __shfl(s4[1], 0, 64);
    const float tot2 = __shfl(s4[2], 0, 64);
    const float tot3 = __shfl(s4[3], 0, 64);
    s4[0] += tot1 + tot2 + tot3;
    s4[1] += tot2 + tot3;
    s4[2] += tot3;

    #pragma unroll
    for (int r = 0; r < 4; ++r) {
        const int p = cbase + (r << 6) + lane;
        wsT[p] = __uint_as_float((u32)(key[r] >> 32));
        wsS[p] = s4[r];
    }
}

// ---------------- K1: all-CU LDS search + fused loss reduce ----------------
__global__ void __launch_bounds__(THREADS, 4) cox_search(
        const float* __restrict__ y_hat, const float* __restrict__ y,
        const float* __restrict__ wsT, const float* __restrict__ wsS,
        float* __restrict__ out, int n) {
    __shared__ __align__(16) float sT[N_];   // 64 KB sorted T
    __shared__ __align__(16) float sS[N_];   // 64 KB suffix sums
    __shared__ float part[16][IPB];          // 4 KB

    const int tid   = threadIdx.x;
    const int lane  = tid & 63;
    const int wv    = tid >> 6;              // 0..15
    const int b     = blockIdx.x;
    const int i     = b * IPB + lane;

    // hoist this thread's scalars (also reused by the wave-0 tail)
    const float yv = y[i];
    const float Ti = fabsf(yv);
    const float yh = y_hat[i];
    const float E  = (yv > 0.0f) ? 1.0f : 0.0f;

    // async-stage both tables into LDS: 16 B/lane, linear, no VGPR round-trip
    {
        const float4* gT = (const float4*)wsT;
        const float4* gS = (const float4*)wsS;
        float4* lT = (float4*)sT;
        float4* lS = (float4*)sS;
        const int wbase = wv << 6;               // wave-uniform float4 base
        #pragma unroll
        for (int t = 0; t < 4; ++t) {
            const int kb = t * 1024 + wbase;     // wave-uniform
            const int k  = kb + lane;            // per-lane global element
            g2l16(&gT[k], &lT[kb]);
            g2l16(&gS[k], &lS[kb]);
        }
    }
    __syncthreads();   // drains vmcnt (compiler emits s_waitcnt before barrier)

    // search: group wv handles chunks 4wv..4wv+3 for its i
    float racc = 0.0f;
    #pragma unroll
    for (int cc = 0; cc < 4; ++cc) {
        const int c = (wv << 2) + cc;
        const float* Tc = &sT[c << 8];
        int pos = 0;
        #pragma unroll
        for (int half = CSZ >> 1; half >= 1; half >>= 1)
            if (Tc[pos + half - 1] < Ti) pos += half;
        if (Tc[pos] < Ti) pos += 1;
        racc += (pos < CSZ) ? sS[(c << 8) + pos] : 0.0f;
    }
    part[wv][lane] = racc;
    __syncthreads();

    // tail: wave 0 only; its (yh, E) registers correspond to ii == i
    if (tid < IPB) {
        float risk = 0.0f;
        #pragma unroll
        for (int g2 = 0; g2 < 16; ++g2) risk += part[g2][tid];
        float term = (yh - logf(risk)) * E;
        #pragma unroll
        for (int off = 32; off >= 1; off >>= 1)
            term += __shfl_down(term, off, 64);
        if (tid == 0) atomicAdd(out, -term / (float)n);
    }
}

extern "C" void kernel_launch(void* const* d_in, const int* in_sizes, int n_in,
                              void* d_out, int out_size, void* d_ws, size_t ws_size,
                              hipStream_t stream) {
    const float* y_hat = (const float*)d_in[0];
    const float* y     = (const float*)d_in[1];
    float* out = (float*)d_out;
    const int n = in_sizes[0];   // 16384

    float* wsT = (float*)d_ws;               // 16384 floats
    float* wsS = wsT + N_;                   // 16384 floats

    cox_sort<<<NCH, 64, 0, stream>>>(y_hat, y, wsT, wsS, out);
    cox_search<<<N_ / IPB, THREADS, 0, stream>>>(y_hat, y, wsT, wsS, out, n);
}